// Round 4
// baseline (468.702 us; speedup 1.0000x reference)
//
#include <hip/hip_runtime.h>

typedef unsigned short u16;
typedef __attribute__((ext_vector_type(8))) short bf16x8_t;
typedef __attribute__((ext_vector_type(4))) float f32x4_t;

__device__ __forceinline__ u16 f2bf(float x){
  union { float f; unsigned u; } v; v.f = x;
  unsigned r = v.u + 0x7FFFu + ((v.u >> 16) & 1u);
  return (u16)(r >> 16);
}
__device__ __forceinline__ float bf2f(u16 h){
  union { unsigned u; float f; } v; v.u = ((unsigned)h) << 16;
  return v.f;
}
__device__ __forceinline__ u16 hi16(float x){
  union { float f; unsigned u; } v; v.f = x;
  return (u16)(v.u >> 16);          // truncation: bias cancels in renormalization
}

// async global->LDS DMA, 16B/lane; data lands at base + lane*16.
__device__ __forceinline__ void gl2lds16(const u16* g, u16* l){
  __builtin_amdgcn_global_load_lds((const __attribute__((address_space(1))) void*)g,
                                   (__attribute__((address_space(3))) void*)l, 16, 0, 0);
}

// ---- prep: X=[gene|expr] hi/lo split (blocks 0..8191) + all W transposes (8192..8575)
__global__ __launch_bounds__(256) void prep_kernel(
    const float* __restrict__ gene, const float* __restrict__ expr,
    const float* __restrict__ Wf, const float* __restrict__ Wq,
    const float* __restrict__ Wk, const float* __restrict__ Wv,
    const float* __restrict__ Wo,
    u16* __restrict__ Xh, u16* __restrict__ Xl,
    u16* __restrict__ Wfth, u16* __restrict__ Wftl,
    u16* __restrict__ Wqth, u16* __restrict__ Wkth,
    u16* __restrict__ Wvth, u16* __restrict__ Woth)
{
  __shared__ float t[64][65];
  int tid = threadIdx.x;
  if (blockIdx.x < 8192){
    size_t e = ((size_t)blockIdx.x * 256 + tid) * 4;
    int row = (int)(e >> 10);
    int col = (int)(e & 1023);
    const float* src = (col < 512) ? (gene + (size_t)row * 512 + col)
                                   : (expr + (size_t)row * 512 + (col - 512));
    float4 v = *(const float4*)src;
    float a[4] = {v.x, v.y, v.z, v.w};
    u16 hs[4], ls[4];
#pragma unroll
    for (int i = 0; i < 4; i++){
      hs[i] = f2bf(a[i]);
      ls[i] = f2bf(a[i] - bf2f(hs[i]));
    }
    *(uint2*)(Xh + e) = make_uint2(hs[0] | ((unsigned)hs[1] << 16), hs[2] | ((unsigned)hs[3] << 16));
    *(uint2*)(Xl + e) = make_uint2(ls[0] | ((unsigned)ls[1] << 16), ls[2] | ((unsigned)ls[3] << 16));
    return;
  }
  int id = blockIdx.x - 8192;
  const float* W; u16* Th; u16* Tl; int K, kx, ny;
  if (id < 128){ W = Wf; Th = Wfth; Tl = Wftl; K = 1024; kx = id >> 3; ny = id & 7; }
  else {
    int tt = id - 128; int wi = tt >> 6; tt &= 63; kx = tt >> 3; ny = tt & 7; K = 512;
    W  = (wi == 0) ? Wq  : (wi == 1) ? Wk  : (wi == 2) ? Wv  : Wo;
    Th = (wi == 0) ? Wqth: (wi == 1) ? Wkth: (wi == 2) ? Wvth: Woth;
    Tl = nullptr;
  }
  int k0 = kx * 64, n0 = ny * 64;
  int r = tid >> 4;
  int c4 = (tid & 15) * 4;
#pragma unroll
  for (int p = 0; p < 4; p++){
    int k = p * 16 + r;
    float4 v = *(const float4*)(W + (size_t)(k0 + k) * 512 + n0 + c4);
    t[c4 + 0][k] = v.x; t[c4 + 1][k] = v.y; t[c4 + 2][k] = v.z; t[c4 + 3][k] = v.w;
  }
  __syncthreads();
#pragma unroll
  for (int p = 0; p < 4; p++){
    int n = p * 16 + r;
    u16 hs[4], ls[4];
#pragma unroll
    for (int i = 0; i < 4; i++){
      float x = t[n][c4 + i];
      hs[i] = f2bf(x);
      ls[i] = f2bf(x - bf2f(hs[i]));
    }
    size_t o = (size_t)(n0 + n) * K + k0 + c4;
    *(uint2*)(Th + o) = make_uint2(hs[0] | ((unsigned)hs[1] << 16), hs[2] | ((unsigned)hs[3] << 16));
    if (Tl)
      *(uint2*)(Tl + o) = make_uint2(ls[0] | ((unsigned)ls[1] << 16), ls[2] | ((unsigned)ls[3] << 16));
  }
}

// ---- GEMM core: BM=128 BN=64 BK=64 (2x32 halves), 4 waves (2x2 of 64x32) ----
// SPLITS: 3 = aH*bH+aH*bL+aL*bH ; 2 = aH*bH+aL*bH ; 1 = aH*bH
// LDS per matrix: halves of 32 k, row-major [rows][32], XOR-swizzled 16B granules.
template<int SPLITS>
__device__ __forceinline__ void gemm_core(
    const u16* __restrict__ Ah, const u16* __restrict__ Al, int lda,
    const u16* __restrict__ Bh, const u16* __restrict__ Bl, int K,
    int m0, int n0, f32x4_t (&acc)[4][2],
    u16* sAh, u16* sAl, u16* sBh, u16* sBl)
{
  int tid = threadIdx.x;
  int lane = tid & 63, w = tid >> 6, quad = lane >> 4, l15 = lane & 15;
  int wm = w & 1, wn = w >> 1;
  int lrow = lane >> 2;
  int swzS = ((lane >> 2) & 3) ^ ((lane >> 4) & 3);
  int gkq  = ((lane & 3) ^ swzS) * 8;
  const u16* pA0 = Ah + (size_t)(m0 + w * 32 + lrow) * lda + gkq;
  const u16* pA1 = Ah + (size_t)(m0 + w * 32 + 16 + lrow) * lda + gkq;
  const u16* pL0 = (SPLITS >= 2) ? Al + (size_t)(m0 + w * 32 + lrow) * lda + gkq : nullptr;
  const u16* pL1 = (SPLITS >= 2) ? Al + (size_t)(m0 + w * 32 + 16 + lrow) * lda + gkq : nullptr;
  const u16* pB0 = Bh + (size_t)(n0 + w * 16 + lrow) * K + gkq;
  const u16* pBl = (SPLITS == 3) ? Bl + (size_t)(n0 + w * 16 + lrow) * K + gkq : nullptr;
  u16* dA  = sAh + w * 1024;
  u16* dAl = (SPLITS >= 2) ? sAl + w * 1024 : nullptr;
  u16* dB  = sBh + w * 512;
  u16* dBl = (SPLITS == 3) ? sBl + w * 512 : nullptr;
  int pq = (quad ^ ((l15 & 3) ^ ((l15 >> 2) & 3))) * 8;

  for (int k0 = 0; k0 < K; k0 += 64){
    __syncthreads();
#pragma unroll
    for (int hf = 0; hf < 2; hf++){
      gl2lds16(pA0 + k0 + hf * 32, dA + hf * 4096);
      gl2lds16(pA1 + k0 + hf * 32, dA + hf * 4096 + 512);
      if constexpr (SPLITS >= 2){
        gl2lds16(pL0 + k0 + hf * 32, dAl + hf * 4096);
        gl2lds16(pL1 + k0 + hf * 32, dAl + hf * 4096 + 512);
      }
      gl2lds16(pB0 + k0 + hf * 32, dB + hf * 2048);
      if constexpr (SPLITS == 3)
        gl2lds16(pBl + k0 + hf * 32, dBl + hf * 2048);
    }
    __syncthreads();

#pragma unroll
    for (int hf = 0; hf < 2; hf++){
      bf16x8_t aH[4], aL[4], bH[2], bL[2];
#pragma unroll
      for (int mi = 0; mi < 4; mi++){
        int ad = (wm * 64 + mi * 16 + l15) * 32 + pq + hf * 4096;
        aH[mi] = *(const bf16x8_t*)&sAh[ad];
        if constexpr (SPLITS >= 2) aL[mi] = *(const bf16x8_t*)&sAl[ad];
      }
#pragma unroll
      for (int ni = 0; ni < 2; ni++){
        int bd = (wn * 32 + ni * 16 + l15) * 32 + pq + hf * 2048;
        bH[ni] = *(const bf16x8_t*)&sBh[bd];
        if constexpr (SPLITS == 3) bL[ni] = *(const bf16x8_t*)&sBl[bd];
      }
#pragma unroll
      for (int mi = 0; mi < 4; mi++)
#pragma unroll
        for (int ni = 0; ni < 2; ni++){
          acc[mi][ni] = __builtin_amdgcn_mfma_f32_16x16x32_bf16(aH[mi], bH[ni], acc[mi][ni], 0, 0, 0);
          if constexpr (SPLITS == 3)
            acc[mi][ni] = __builtin_amdgcn_mfma_f32_16x16x32_bf16(aH[mi], bL[ni], acc[mi][ni], 0, 0, 0);
          if constexpr (SPLITS >= 2)
            acc[mi][ni] = __builtin_amdgcn_mfma_f32_16x16x32_bf16(aL[mi], bH[ni], acc[mi][ni], 0, 0, 0);
        }
    }
  }
}

// fused = X @ Wf + bf -> split bf16 (Fh, Fl). grid (64, 8)
__global__ __launch_bounds__(256, 2) void gemm_fused_kernel(
    const u16* __restrict__ Xh, const u16* __restrict__ Xl,
    const u16* __restrict__ Wfth, const u16* __restrict__ Wftl,
    const float* __restrict__ bias, u16* __restrict__ Fh, u16* __restrict__ Fl)
{
  __shared__ __align__(16) u16 sAh[128 * 64], sAl[128 * 64], sBh[64 * 64], sBl[64 * 64];
  int m0 = blockIdx.x * 128, n0 = blockIdx.y * 64;
  f32x4_t acc[4][2];
#pragma unroll
  for (int i = 0; i < 4; i++)
#pragma unroll
    for (int j = 0; j < 2; j++)
#pragma unroll
      for (int r = 0; r < 4; r++) acc[i][j][r] = 0.f;
  gemm_core<3>(Xh, Xl, 1024, Wfth, Wftl, 1024, m0, n0, acc, sAh, sAl, sBh, sBl);

  int lane = threadIdx.x & 63, w = threadIdx.x >> 6, quad = lane >> 4, l15 = lane & 15;
  int wm = w & 1, wn = w >> 1;
#pragma unroll
  for (int mi = 0; mi < 4; mi++)
#pragma unroll
    for (int ni = 0; ni < 2; ni++){
      int gn = n0 + wn * 32 + ni * 16 + l15;
      float bs = bias[gn];
      int gm0 = m0 + wm * 64 + mi * 16 + quad * 4;
#pragma unroll
      for (int r = 0; r < 4; r++){
        float v = acc[mi][ni][r] + bs;
        u16 hb = f2bf(v);
        Fh[(size_t)(gm0 + r) * 512 + gn] = hb;
        Fl[(size_t)(gm0 + r) * 512 + gn] = f2bf(v - bf2f(hb));
      }
    }
}

// Q|K|V in one launch. grid (64, 24): side = y>>3 (0=Q,1=K,2=V), n0=(y&7)*64
__global__ __launch_bounds__(256, 2) void gemm_qkv_kernel(
    const u16* __restrict__ Fh, const u16* __restrict__ Fl,
    const u16* __restrict__ Xeh, const u16* __restrict__ Xel,   // expr half of X, lda 1024
    const u16* __restrict__ Wqth, const u16* __restrict__ Wkth, const u16* __restrict__ Wvth,
    const float* __restrict__ bq, const float* __restrict__ bk, const float* __restrict__ bv,
    u16* __restrict__ Q, u16* __restrict__ Kout, u16* __restrict__ Vt, float qsc)
{
  __shared__ __align__(16) u16 sAh[128 * 64], sAl[128 * 64], sBh[64 * 64];
  int side = blockIdx.y >> 3;
  int m0 = blockIdx.x * 128, n0 = (blockIdx.y & 7) * 64;
  const u16* Ah = (side == 2) ? Xeh : Fh;
  const u16* Al = (side == 2) ? Xel : Fl;
  int lda = (side == 2) ? 1024 : 512;
  const u16* Bh = (side == 0) ? Wqth : (side == 1) ? Wkth : Wvth;
  const float* bias = (side == 0) ? bq : (side == 1) ? bk : bv;

  f32x4_t acc[4][2];
#pragma unroll
  for (int i = 0; i < 4; i++)
#pragma unroll
    for (int j = 0; j < 2; j++)
#pragma unroll
      for (int r = 0; r < 4; r++) acc[i][j][r] = 0.f;
  gemm_core<2>(Ah, Al, lda, Bh, nullptr, 512, m0, n0, acc, sAh, sAl, sBh, nullptr);

  int lane = threadIdx.x & 63, w = threadIdx.x >> 6, quad = lane >> 4, l15 = lane & 15;
  int wm = w & 1, wn = w >> 1;
#pragma unroll
  for (int mi = 0; mi < 4; mi++)
#pragma unroll
    for (int ni = 0; ni < 2; ni++){
      int gn = n0 + wn * 32 + ni * 16 + l15;
      float bs = bias[gn];
      int gm0 = m0 + wm * 64 + mi * 16 + quad * 4;
#pragma unroll
      for (int r = 0; r < 4; r++){
        float v = acc[mi][ni][r] + bs;
        int gm = gm0 + r;
        if (side == 0){
          Q[(size_t)gm * 512 + gn] = f2bf(v * qsc);
        } else if (side == 1){
          Kout[(size_t)gm * 512 + gn] = f2bf(v);
        } else {
          int bb = gm >> 11, s = gm & 2047;
          int hh = gn >> 6, d = gn & 63;
          Vt[((size_t)((bb * 8 + hh) * 64 + d) << 11) + s] = f2bf(v);
        }
      }
    }
}

// out = O @ Wo + bo -> f32. grid (64, 8)
__global__ __launch_bounds__(256, 2) void gemm_o_kernel(
    const u16* __restrict__ Oh, const u16* __restrict__ Woth,
    const float* __restrict__ bias, float* __restrict__ out)
{
  __shared__ __align__(16) u16 sAh[128 * 64], sBh[64 * 64];
  int m0 = blockIdx.x * 128, n0 = blockIdx.y * 64;
  f32x4_t acc[4][2];
#pragma unroll
  for (int i = 0; i < 4; i++)
#pragma unroll
    for (int j = 0; j < 2; j++)
#pragma unroll
      for (int r = 0; r < 4; r++) acc[i][j][r] = 0.f;
  gemm_core<1>(Oh, nullptr, 512, Woth, nullptr, 512, m0, n0, acc, sAh, nullptr, sBh, nullptr);

  int lane = threadIdx.x & 63, w = threadIdx.x >> 6, quad = lane >> 4, l15 = lane & 15;
  int wm = w & 1, wn = w >> 1;
#pragma unroll
  for (int mi = 0; mi < 4; mi++)
#pragma unroll
    for (int ni = 0; ni < 2; ni++){
      int gn = n0 + wn * 32 + ni * 16 + l15;
      float bs = bias[gn];
      int gm0 = m0 + wm * 64 + mi * 16 + quad * 4;
#pragma unroll
      for (int r = 0; r < 4; r++)
        out[(size_t)(gm0 + r) * 512 + gn] = acc[mi][ni][r] + bs;
    }
}

// ---- flash attention: BARRIER-FREE. K/V fragments loaded global->register
// (16 rows x 64B contiguous segments, L2-hot). Only LDS use is the wave-private
// P transpose (lgkmcnt, no __syncthreads anywhere).
// Q pre-scaled by 0.125*log2(e); p = M * exp2(s*M); l = sum p; O = (sum p*V)/l.
__global__ __launch_bounds__(256, 3) void flash_kernel(
    const u16* __restrict__ Qh, const u16* __restrict__ Kh,
    const u16* __restrict__ Vt, const float* __restrict__ Mm,
    u16* __restrict__ Oh)
{
  __shared__ __align__(16) u16 sP[64 * 72];
  int tid = threadIdx.x, lane = tid & 63, w = tid >> 6, quad = lane >> 4, l15 = lane & 15;
  int bh = blockIdx.y, b = bh >> 3, h = bh & 7;
  int q0 = blockIdx.x * 64;

  const u16* qp = Qh + ((size_t)(b * 2048 + q0 + w * 16 + l15)) * 512 + h * 64 + quad * 8;
  bf16x8_t qH0 = *(const bf16x8_t*)qp;
  bf16x8_t qH1 = *(const bf16x8_t*)(qp + 32);

  // per-lane base pointers (advance per k-tile)
  const u16* pK[4]; const u16* pV[4]; const float* pM[4];
#pragma unroll
  for (int ni = 0; ni < 4; ni++){
    pK[ni] = Kh + ((size_t)(b * 2048 + ni * 16 + l15)) * 512 + h * 64 + quad * 8;
    pV[ni] = Vt + ((size_t)(bh * 64 + ni * 16 + l15)) * 2048 + quad * 8;
  }
#pragma unroll
  for (int r = 0; r < 4; r++)
    pM[r] = Mm + (size_t)b * 2048 * 2048 + (size_t)(q0 + w * 16 + quad * 4 + r) * 2048 + l15;

  float lp[4] = {0.f, 0.f, 0.f, 0.f};
  f32x4_t Oacc[4];
#pragma unroll
  for (int ni = 0; ni < 4; ni++)
#pragma unroll
    for (int r = 0; r < 4; r++) Oacc[ni][r] = 0.f;

  for (int it = 0; it < 32; ++it){
    // K fragments + M values (independent loads, issued up front)
    bf16x8_t kf[4][2];
#pragma unroll
    for (int ni = 0; ni < 4; ni++){
      kf[ni][0] = *(const bf16x8_t*)(pK[ni]);
      kf[ni][1] = *(const bf16x8_t*)(pK[ni] + 32);
    }
    float Mc[4][4];
#pragma unroll
    for (int ni = 0; ni < 4; ni++)
#pragma unroll
      for (int r = 0; r < 4; r++)
        Mc[ni][r] = pM[r][ni * 16];

    // scores = Q . K^T
    f32x4_t S[4];
#pragma unroll
    for (int ni = 0; ni < 4; ni++)
#pragma unroll
      for (int r = 0; r < 4; r++) S[ni][r] = 0.f;
#pragma unroll
    for (int ni = 0; ni < 4; ni++){
      S[ni] = __builtin_amdgcn_mfma_f32_16x16x32_bf16(qH0, kf[ni][0], S[ni], 0, 0, 0);
      S[ni] = __builtin_amdgcn_mfma_f32_16x16x32_bf16(qH1, kf[ni][1], S[ni], 0, 0, 0);
    }

    // V fragments (issued before the exp section; consumed in PV)
    bf16x8_t vf[4][2];
#pragma unroll
    for (int ni = 0; ni < 4; ni++){
      vf[ni][0] = *(const bf16x8_t*)(pV[ni]);
      vf[ni][1] = *(const bf16x8_t*)(pV[ni] + 32);
    }

    // p = M*exp2(s*M); per-lane l; truncation-store bf16 P to wave-private sP rows
#pragma unroll
    for (int ni = 0; ni < 4; ni++)
#pragma unroll
      for (int r = 0; r < 4; r++){
        float m = Mc[ni][r];
        float p = m * __builtin_amdgcn_exp2f(S[ni][r] * m);
        lp[r] += p;
        sP[(w * 16 + quad * 4 + r) * 72 + ni * 16 + l15] = hi16(p);
      }

    // O += P @ V
#pragma unroll
    for (int ds = 0; ds < 2; ds++){
      bf16x8_t pf = *(const bf16x8_t*)&sP[(w * 16 + l15) * 72 + ds * 32 + quad * 8];
#pragma unroll
      for (int ni = 0; ni < 4; ni++)
        Oacc[ni] = __builtin_amdgcn_mfma_f32_16x16x32_bf16(pf, vf[ni][ds], Oacc[ni], 0, 0, 0);
    }

#pragma unroll
    for (int ni = 0; ni < 4; ni++){
      pK[ni] += 64 * 512;
      pV[ni] += 64;
    }
#pragma unroll
    for (int r = 0; r < 4; r++) pM[r] += 64;
  }

#pragma unroll
  for (int r = 0; r < 4; r++){
#pragma unroll
    for (int off = 1; off < 16; off <<= 1)
      lp[r] += __shfl_xor(lp[r], off);
  }

#pragma unroll
  for (int r = 0; r < 4; r++){
    float inv = 1.0f / lp[r];
    int q = q0 + w * 16 + quad * 4 + r;
    size_t rb = ((size_t)(b * 2048 + q)) * 512 + h * 64;
#pragma unroll
    for (int ni = 0; ni < 4; ni++)
      Oh[rb + ni * 16 + l15] = f2bf(Oacc[ni][r] * inv);
  }
}

extern "C" void kernel_launch(void* const* d_in, const int* in_sizes, int n_in,
                              void* d_out, int out_size, void* d_ws, size_t ws_size,
                              hipStream_t stream)
{
  const float* gene = (const float*)d_in[0];
  const float* expr = (const float*)d_in[1];
  const float* Mm   = (const float*)d_in[2];
  const float* Wf   = (const float*)d_in[3];
  const float* bfv  = (const float*)d_in[4];
  const float* Wq   = (const float*)d_in[5];
  const float* bq   = (const float*)d_in[6];
  const float* Wk   = (const float*)d_in[7];
  const float* bk   = (const float*)d_in[8];
  const float* Wv   = (const float*)d_in[9];
  const float* bv   = (const float*)d_in[10];
  const float* Wo   = (const float*)d_in[11];
  const float* bo   = (const float*)d_in[12];
  float* out = (float*)d_out;

  char* ws = (char*)d_ws;
  size_t off = 0;
  auto alloc = [&](size_t bytes) -> void* {
    void* p = (void*)(ws + off);
    off += (bytes + 255) & ~(size_t)255;
    return p;
  };
  u16* Xh   = (u16*)alloc(8192ull * 1024 * 2);
  u16* Xl   = (u16*)alloc(8192ull * 1024 * 2);
  u16* Wfth = (u16*)alloc(512ull * 1024 * 2);
  u16* Wftl = (u16*)alloc(512ull * 1024 * 2);
  u16* Wqth = (u16*)alloc(512ull * 512 * 2);
  u16* Wkth = (u16*)alloc(512ull * 512 * 2);
  u16* Wvth = (u16*)alloc(512ull * 512 * 2);
  u16* Woth = (u16*)alloc(512ull * 512 * 2);
  u16* Fh   = (u16*)alloc(8192ull * 512 * 2);
  u16* Fl   = (u16*)alloc(8192ull * 512 * 2);
  u16* Qh   = (u16*)alloc(8192ull * 512 * 2);
  u16* Kh   = (u16*)alloc(8192ull * 512 * 2);
  u16* Vt   = (u16*)alloc(8192ull * 512 * 2);
  u16* Oh = Xh;   // X dead after QKV; attention output aliases it

  const float QSC = 0.1803368801f;   // 0.125 * log2(e) — folded into Q, exp via exp2

  prep_kernel<<<8576, 256, 0, stream>>>(gene, expr, Wf, Wq, Wk, Wv, Wo,
                                        Xh, Xl, Wfth, Wftl, Wqth, Wkth, Wvth, Woth);
  gemm_fused_kernel<<<dim3(64, 8), 256, 0, stream>>>(Xh, Xl, Wfth, Wftl, bfv, Fh, Fl);
  gemm_qkv_kernel<<<dim3(64, 24), 256, 0, stream>>>(Fh, Fl, Xh + 512, Xl + 512,
                                                    Wqth, Wkth, Wvth, bq, bk, bv,
                                                    Qh, Kh, Vt, QSC);
  flash_kernel<<<dim3(32, 32), 256, 0, stream>>>(Qh, Kh, Vt, Mm, Oh);
  gemm_o_kernel<<<dim3(64, 8), 256, 0, stream>>>(Oh, Woth, bo, out);

  (void)in_sizes; (void)n_in; (void)out_size; (void)ws_size;
}

// Round 5
// 339.502 us; speedup vs baseline: 1.3806x; 1.3806x over previous
//
#include <hip/hip_runtime.h>

typedef unsigned short u16;
typedef __attribute__((ext_vector_type(8))) short bf16x8_t;
typedef __attribute__((ext_vector_type(4))) float f32x4_t;

__device__ __forceinline__ u16 f2bf(float x){
  union { float f; unsigned u; } v; v.f = x;
  unsigned r = v.u + 0x7FFFu + ((v.u >> 16) & 1u);
  return (u16)(r >> 16);
}
__device__ __forceinline__ float bf2f(u16 h){
  union { unsigned u; float f; } v; v.u = ((unsigned)h) << 16;
  return v.f;
}
__device__ __forceinline__ u16 hi16(float x){
  union { float f; unsigned u; } v; v.f = x;
  return (u16)(v.u >> 16);          // truncation: bias cancels in renormalization
}

// async global->LDS DMA, 16B/lane; data lands at base + lane*16.
__device__ __forceinline__ void gl2lds16(const u16* g, u16* l){
  __builtin_amdgcn_global_load_lds((const __attribute__((address_space(1))) void*)g,
                                   (__attribute__((address_space(3))) void*)l, 16, 0, 0);
}

// ---- prep: X=[gene|expr] hi/lo split (blocks 0..8191) + all W transposes (8192..8575)
__global__ __launch_bounds__(256) void prep_kernel(
    const float* __restrict__ gene, const float* __restrict__ expr,
    const float* __restrict__ Wf, const float* __restrict__ Wq,
    const float* __restrict__ Wk, const float* __restrict__ Wv,
    const float* __restrict__ Wo,
    u16* __restrict__ Xh, u16* __restrict__ Xl,
    u16* __restrict__ Wfth, u16* __restrict__ Wftl,
    u16* __restrict__ Wqth, u16* __restrict__ Wkth,
    u16* __restrict__ Wvth, u16* __restrict__ Woth)
{
  __shared__ float t[64][65];
  int tid = threadIdx.x;
  if (blockIdx.x < 8192){
    size_t e = ((size_t)blockIdx.x * 256 + tid) * 4;
    int row = (int)(e >> 10);
    int col = (int)(e & 1023);
    const float* src = (col < 512) ? (gene + (size_t)row * 512 + col)
                                   : (expr + (size_t)row * 512 + (col - 512));
    float4 v = *(const float4*)src;
    float a[4] = {v.x, v.y, v.z, v.w};
    u16 hs[4], ls[4];
#pragma unroll
    for (int i = 0; i < 4; i++){
      hs[i] = f2bf(a[i]);
      ls[i] = f2bf(a[i] - bf2f(hs[i]));
    }
    *(uint2*)(Xh + e) = make_uint2(hs[0] | ((unsigned)hs[1] << 16), hs[2] | ((unsigned)hs[3] << 16));
    *(uint2*)(Xl + e) = make_uint2(ls[0] | ((unsigned)ls[1] << 16), ls[2] | ((unsigned)ls[3] << 16));
    return;
  }
  int id = blockIdx.x - 8192;
  const float* W; u16* Th; u16* Tl; int K, kx, ny;
  if (id < 128){ W = Wf; Th = Wfth; Tl = Wftl; K = 1024; kx = id >> 3; ny = id & 7; }
  else {
    int tt = id - 128; int wi = tt >> 6; tt &= 63; kx = tt >> 3; ny = tt & 7; K = 512;
    W  = (wi == 0) ? Wq  : (wi == 1) ? Wk  : (wi == 2) ? Wv  : Wo;
    Th = (wi == 0) ? Wqth: (wi == 1) ? Wkth: (wi == 2) ? Wvth: Woth;
    Tl = nullptr;
  }
  int k0 = kx * 64, n0 = ny * 64;
  int r = tid >> 4;
  int c4 = (tid & 15) * 4;
#pragma unroll
  for (int p = 0; p < 4; p++){
    int k = p * 16 + r;
    float4 v = *(const float4*)(W + (size_t)(k0 + k) * 512 + n0 + c4);
    t[c4 + 0][k] = v.x; t[c4 + 1][k] = v.y; t[c4 + 2][k] = v.z; t[c4 + 3][k] = v.w;
  }
  __syncthreads();
#pragma unroll
  for (int p = 0; p < 4; p++){
    int n = p * 16 + r;
    u16 hs[4], ls[4];
#pragma unroll
    for (int i = 0; i < 4; i++){
      float x = t[n][c4 + i];
      hs[i] = f2bf(x);
      ls[i] = f2bf(x - bf2f(hs[i]));
    }
    size_t o = (size_t)(n0 + n) * K + k0 + c4;
    *(uint2*)(Th + o) = make_uint2(hs[0] | ((unsigned)hs[1] << 16), hs[2] | ((unsigned)hs[3] << 16));
    if (Tl)
      *(uint2*)(Tl + o) = make_uint2(ls[0] | ((unsigned)ls[1] << 16), ls[2] | ((unsigned)ls[3] << 16));
  }
}

// ---- GEMM core: BM=128 BN=64 BK=64 (2x32 halves), 4 waves (2x2 of 64x32) ----
// SPLITS: 3 = aH*bH+aH*bL+aL*bH ; 2 = aH*bH+aL*bH ; 1 = aH*bH
// LDS per matrix: halves of 32 k, row-major [rows][32], XOR-swizzled 16B granules.
template<int SPLITS>
__device__ __forceinline__ void gemm_core(
    const u16* __restrict__ Ah, const u16* __restrict__ Al, int lda,
    const u16* __restrict__ Bh, const u16* __restrict__ Bl, int K,
    int m0, int n0, f32x4_t (&acc)[4][2],
    u16* sAh, u16* sAl, u16* sBh, u16* sBl)
{
  int tid = threadIdx.x;
  int lane = tid & 63, w = tid >> 6, quad = lane >> 4, l15 = lane & 15;
  int wm = w & 1, wn = w >> 1;
  int lrow = lane >> 2;
  int swzS = ((lane >> 2) & 3) ^ ((lane >> 4) & 3);
  int gkq  = ((lane & 3) ^ swzS) * 8;
  const u16* pA0 = Ah + (size_t)(m0 + w * 32 + lrow) * lda + gkq;
  const u16* pA1 = Ah + (size_t)(m0 + w * 32 + 16 + lrow) * lda + gkq;
  const u16* pL0 = (SPLITS >= 2) ? Al + (size_t)(m0 + w * 32 + lrow) * lda + gkq : nullptr;
  const u16* pL1 = (SPLITS >= 2) ? Al + (size_t)(m0 + w * 32 + 16 + lrow) * lda + gkq : nullptr;
  const u16* pB0 = Bh + (size_t)(n0 + w * 16 + lrow) * K + gkq;
  const u16* pBl = (SPLITS == 3) ? Bl + (size_t)(n0 + w * 16 + lrow) * K + gkq : nullptr;
  u16* dA  = sAh + w * 1024;
  u16* dAl = (SPLITS >= 2) ? sAl + w * 1024 : nullptr;
  u16* dB  = sBh + w * 512;
  u16* dBl = (SPLITS == 3) ? sBl + w * 512 : nullptr;
  int pq = (quad ^ ((l15 & 3) ^ ((l15 >> 2) & 3))) * 8;

  for (int k0 = 0; k0 < K; k0 += 64){
    __syncthreads();
#pragma unroll
    for (int hf = 0; hf < 2; hf++){
      gl2lds16(pA0 + k0 + hf * 32, dA + hf * 4096);
      gl2lds16(pA1 + k0 + hf * 32, dA + hf * 4096 + 512);
      if constexpr (SPLITS >= 2){
        gl2lds16(pL0 + k0 + hf * 32, dAl + hf * 4096);
        gl2lds16(pL1 + k0 + hf * 32, dAl + hf * 4096 + 512);
      }
      gl2lds16(pB0 + k0 + hf * 32, dB + hf * 2048);
      if constexpr (SPLITS == 3)
        gl2lds16(pBl + k0 + hf * 32, dBl + hf * 2048);
    }
    __syncthreads();

#pragma unroll
    for (int hf = 0; hf < 2; hf++){
      bf16x8_t aH[4], aL[4], bH[2], bL[2];
#pragma unroll
      for (int mi = 0; mi < 4; mi++){
        int ad = (wm * 64 + mi * 16 + l15) * 32 + pq + hf * 4096;
        aH[mi] = *(const bf16x8_t*)&sAh[ad];
        if constexpr (SPLITS >= 2) aL[mi] = *(const bf16x8_t*)&sAl[ad];
      }
#pragma unroll
      for (int ni = 0; ni < 2; ni++){
        int bd = (wn * 32 + ni * 16 + l15) * 32 + pq + hf * 2048;
        bH[ni] = *(const bf16x8_t*)&sBh[bd];
        if constexpr (SPLITS == 3) bL[ni] = *(const bf16x8_t*)&sBl[bd];
      }
#pragma unroll
      for (int mi = 0; mi < 4; mi++)
#pragma unroll
        for (int ni = 0; ni < 2; ni++){
          acc[mi][ni] = __builtin_amdgcn_mfma_f32_16x16x32_bf16(aH[mi], bH[ni], acc[mi][ni], 0, 0, 0);
          if constexpr (SPLITS == 3)
            acc[mi][ni] = __builtin_amdgcn_mfma_f32_16x16x32_bf16(aH[mi], bL[ni], acc[mi][ni], 0, 0, 0);
          if constexpr (SPLITS >= 2)
            acc[mi][ni] = __builtin_amdgcn_mfma_f32_16x16x32_bf16(aL[mi], bH[ni], acc[mi][ni], 0, 0, 0);
        }
    }
  }
}

// fused = X @ Wf + bf -> split bf16 (Fh, Fl). grid (64, 8)
__global__ __launch_bounds__(256, 2) void gemm_fused_kernel(
    const u16* __restrict__ Xh, const u16* __restrict__ Xl,
    const u16* __restrict__ Wfth, const u16* __restrict__ Wftl,
    const float* __restrict__ bias, u16* __restrict__ Fh, u16* __restrict__ Fl)
{
  __shared__ __align__(16) u16 sAh[128 * 64], sAl[128 * 64], sBh[64 * 64], sBl[64 * 64];
  int m0 = blockIdx.x * 128, n0 = blockIdx.y * 64;
  f32x4_t acc[4][2];
#pragma unroll
  for (int i = 0; i < 4; i++)
#pragma unroll
    for (int j = 0; j < 2; j++)
#pragma unroll
      for (int r = 0; r < 4; r++) acc[i][j][r] = 0.f;
  gemm_core<3>(Xh, Xl, 1024, Wfth, Wftl, 1024, m0, n0, acc, sAh, sAl, sBh, sBl);

  int lane = threadIdx.x & 63, w = threadIdx.x >> 6, quad = lane >> 4, l15 = lane & 15;
  int wm = w & 1, wn = w >> 1;
#pragma unroll
  for (int mi = 0; mi < 4; mi++)
#pragma unroll
    for (int ni = 0; ni < 2; ni++){
      int gn = n0 + wn * 32 + ni * 16 + l15;
      float bs = bias[gn];
      int gm0 = m0 + wm * 64 + mi * 16 + quad * 4;
#pragma unroll
      for (int r = 0; r < 4; r++){
        float v = acc[mi][ni][r] + bs;
        u16 hb = f2bf(v);
        Fh[(size_t)(gm0 + r) * 512 + gn] = hb;
        Fl[(size_t)(gm0 + r) * 512 + gn] = f2bf(v - bf2f(hb));
      }
    }
}

// Q|K|V in one launch. grid (64, 24): side = y>>3 (0=Q,1=K,2=V), n0=(y&7)*64
__global__ __launch_bounds__(256, 2) void gemm_qkv_kernel(
    const u16* __restrict__ Fh, const u16* __restrict__ Fl,
    const u16* __restrict__ Xeh, const u16* __restrict__ Xel,   // expr half of X, lda 1024
    const u16* __restrict__ Wqth, const u16* __restrict__ Wkth, const u16* __restrict__ Wvth,
    const float* __restrict__ bq, const float* __restrict__ bk, const float* __restrict__ bv,
    u16* __restrict__ Q, u16* __restrict__ Kout, u16* __restrict__ Vt, float qsc)
{
  __shared__ __align__(16) u16 sAh[128 * 64], sAl[128 * 64], sBh[64 * 64];
  int side = blockIdx.y >> 3;
  int m0 = blockIdx.x * 128, n0 = (blockIdx.y & 7) * 64;
  const u16* Ah = (side == 2) ? Xeh : Fh;
  const u16* Al = (side == 2) ? Xel : Fl;
  int lda = (side == 2) ? 1024 : 512;
  const u16* Bh = (side == 0) ? Wqth : (side == 1) ? Wkth : Wvth;
  const float* bias = (side == 0) ? bq : (side == 1) ? bk : bv;

  f32x4_t acc[4][2];
#pragma unroll
  for (int i = 0; i < 4; i++)
#pragma unroll
    for (int j = 0; j < 2; j++)
#pragma unroll
      for (int r = 0; r < 4; r++) acc[i][j][r] = 0.f;
  gemm_core<2>(Ah, Al, lda, Bh, nullptr, 512, m0, n0, acc, sAh, sAl, sBh, nullptr);

  int lane = threadIdx.x & 63, w = threadIdx.x >> 6, quad = lane >> 4, l15 = lane & 15;
  int wm = w & 1, wn = w >> 1;
#pragma unroll
  for (int mi = 0; mi < 4; mi++)
#pragma unroll
    for (int ni = 0; ni < 2; ni++){
      int gn = n0 + wn * 32 + ni * 16 + l15;
      float bs = bias[gn];
      int gm0 = m0 + wm * 64 + mi * 16 + quad * 4;
#pragma unroll
      for (int r = 0; r < 4; r++){
        float v = acc[mi][ni][r] + bs;
        int gm = gm0 + r;
        if (side == 0){
          Q[(size_t)gm * 512 + gn] = f2bf(v * qsc);
        } else if (side == 1){
          Kout[(size_t)gm * 512 + gn] = f2bf(v);
        } else {
          int bb = gm >> 11, s = gm & 2047;
          int hh = gn >> 6, d = gn & 63;
          Vt[((size_t)((bb * 8 + hh) * 64 + d) << 11) + s] = f2bf(v);
        }
      }
    }
}

// out = O @ Wo + bo -> f32. grid (64, 8)
__global__ __launch_bounds__(256, 2) void gemm_o_kernel(
    const u16* __restrict__ Oh, const u16* __restrict__ Woth,
    const float* __restrict__ bias, float* __restrict__ out)
{
  __shared__ __align__(16) u16 sAh[128 * 64], sBh[64 * 64];
  int m0 = blockIdx.x * 128, n0 = blockIdx.y * 64;
  f32x4_t acc[4][2];
#pragma unroll
  for (int i = 0; i < 4; i++)
#pragma unroll
    for (int j = 0; j < 2; j++)
#pragma unroll
      for (int r = 0; r < 4; r++) acc[i][j][r] = 0.f;
  gemm_core<1>(Oh, nullptr, 512, Woth, nullptr, 512, m0, n0, acc, sAh, nullptr, sBh, nullptr);

  int lane = threadIdx.x & 63, w = threadIdx.x >> 6, quad = lane >> 4, l15 = lane & 15;
  int wm = w & 1, wn = w >> 1;
#pragma unroll
  for (int mi = 0; mi < 4; mi++)
#pragma unroll
    for (int ni = 0; ni < 2; ni++){
      int gn = n0 + wn * 32 + ni * 16 + l15;
      float bs = bias[gn];
      int gm0 = m0 + wm * 64 + mi * 16 + quad * 4;
#pragma unroll
      for (int r = 0; r < 4; r++)
        out[(size_t)(gm0 + r) * 512 + gn] = acc[mi][ni][r] + bs;
    }
}

// ---- flash attention: LDS-staged K/V, DOUBLE-BUFFERED, ONE barrier per iter.
// Pipeline: barrier -> issue gl2lds for tile i+1 into alt buffer -> compute tile i.
// The compiler's vmcnt(0)-before-barrier then drains loads issued a full compute
// phase earlier (near-free), instead of freshly-issued ones (round-3's stall).
// Q pre-scaled by 0.125*log2(e); p = M*exp2(s*M); l = sum p; O = (sum p*V)/l.
// grid (32, 32), 256 thr = 4 waves x 16 q-rows; 41.2 KB LDS -> 3 blocks/CU.
__global__ __launch_bounds__(256, 3) void flash_kernel(
    const u16* __restrict__ Qh, const u16* __restrict__ Kh,
    const u16* __restrict__ Vt, const float* __restrict__ Mm,
    u16* __restrict__ Oh)
{
  __shared__ __align__(16) u16 sKh[2 * 4096], sVt[2 * 4096];
  __shared__ __align__(16) u16 sP[64 * 72];
  int tid = threadIdx.x, lane = tid & 63, w = tid >> 6, quad = lane >> 4, l15 = lane & 15;
  int bh = blockIdx.y, b = bh >> 3, h = bh & 7;
  int q0 = blockIdx.x * 64;

  int qrow = q0 + w * 16 + l15;
  const u16* qp = Qh + ((size_t)(b * 2048 + qrow)) * 512 + h * 64 + quad * 8;
  bf16x8_t qH[2];
  qH[0] = *(const bf16x8_t*)qp;  qH[1] = *(const bf16x8_t*)(qp + 32);

  float lp[4] = {0.f, 0.f, 0.f, 0.f};
  f32x4_t Oacc[4];
#pragma unroll
  for (int ni = 0; ni < 4; ni++)
#pragma unroll
    for (int r = 0; r < 4; r++) Oacc[ni][r] = 0.f;

  // staging lane constants: rows w*16+srow(+8), granule (lane&7) holds col
  // granule ((lane&7) ^ (srow&7)) -> fragment reads are 2-way bank aliased.
  int srow = lane >> 3;
  int gc = ((lane & 7) ^ srow) * 8;
  const u16* gKh0 = Kh + ((size_t)(b * 2048 + w * 16 + srow)) * 512 + h * 64 + gc;
  const u16* gVt0 = Vt + ((size_t)(bh * 64 + w * 16 + srow)) * 2048 + gc;
  const float* Mbase = Mm + (size_t)b * 2048 * 2048 + (size_t)(q0 + w * 16) * 2048;

  // prologue: stage tile 0 into buffer 0
  gl2lds16(gKh0,            sKh + w * 1024);
  gl2lds16(gKh0 + 8 * 512,  sKh + w * 1024 + 512);
  gl2lds16(gVt0,            sVt + w * 1024);
  gl2lds16(gVt0 + 8 * 2048, sVt + w * 1024 + 512);

  // M for tile 0
  float Mc[4][4];
#pragma unroll
  for (int ni = 0; ni < 4; ni++)
#pragma unroll
    for (int r = 0; r < 4; r++)
      Mc[ni][r] = Mbase[(size_t)(quad * 4 + r) * 2048 + ni * 16 + l15];

  int sw7 = l15 & 7;
  for (int it = 0; it < 32; ++it){
    int k0 = it * 64;
    const u16* cK = sKh + (it & 1) * 4096;
    const u16* cV = sVt + (it & 1) * 4096;
    __syncthreads();   // drains tile-i loads (issued one compute phase ago)

    bool hasNext = (it + 1) < 32;
    if (hasNext){
      int kn = k0 + 64;
      u16* nK = sKh + ((it + 1) & 1) * 4096 + w * 1024;
      u16* nV = sVt + ((it + 1) & 1) * 4096 + w * 1024;
      gl2lds16(gKh0 + (size_t)kn * 512,       nK);
      gl2lds16(gKh0 + (size_t)(kn + 8) * 512, nK + 512);
      gl2lds16(gVt0 + kn,                     nV);
      gl2lds16(gVt0 + 8 * 2048 + kn,          nV + 512);
    }

    // prefetch next tile's M into registers (consumed next iteration)
    float Mn[4][4];
    if (hasNext){
#pragma unroll
      for (int ni = 0; ni < 4; ni++)
#pragma unroll
        for (int r = 0; r < 4; r++)
          Mn[ni][r] = Mbase[(size_t)(quad * 4 + r) * 2048 + (k0 + 64) + ni * 16 + l15];
    }

    // scores = Q . K^T (bf16)
    f32x4_t S[4];
#pragma unroll
    for (int ni = 0; ni < 4; ni++)
#pragma unroll
      for (int r = 0; r < 4; r++) S[ni][r] = 0.f;
#pragma unroll
    for (int ni = 0; ni < 4; ni++){
      int kb = (ni * 16 + l15) * 64;
#pragma unroll
      for (int ds = 0; ds < 2; ds++){
        int p = ((ds * 4 + quad) ^ sw7) * 8;
        bf16x8_t kf = *(const bf16x8_t*)&cK[kb + p];
        S[ni] = __builtin_amdgcn_mfma_f32_16x16x32_bf16(qH[ds], kf, S[ni], 0, 0, 0);
      }
    }

    // p = M*exp2(s*M); per-lane l; truncation-store bf16 P (wave-private rows)
#pragma unroll
    for (int ni = 0; ni < 4; ni++)
#pragma unroll
      for (int r = 0; r < 4; r++){
        float m = Mc[ni][r];
        float p = m * __builtin_amdgcn_exp2f(S[ni][r] * m);
        lp[r] += p;
        sP[(w * 16 + quad * 4 + r) * 72 + ni * 16 + l15] = hi16(p);
      }

    // O += P @ V (wave-private sP rows; lgkmcnt only, no barrier)
#pragma unroll
    for (int ds = 0; ds < 2; ds++){
      bf16x8_t pf = *(const bf16x8_t*)&sP[(w * 16 + l15) * 72 + ds * 32 + quad * 8];
#pragma unroll
      for (int ni = 0; ni < 4; ni++){
        int p = ((ds * 4 + quad) ^ sw7) * 8;
        bf16x8_t vf = *(const bf16x8_t*)&cV[(ni * 16 + l15) * 64 + p];
        Oacc[ni] = __builtin_amdgcn_mfma_f32_16x16x32_bf16(pf, vf, Oacc[ni], 0, 0, 0);
      }
    }

    if (hasNext){
#pragma unroll
      for (int ni = 0; ni < 4; ni++)
#pragma unroll
        for (int r = 0; r < 4; r++) Mc[ni][r] = Mn[ni][r];
    }
  }

#pragma unroll
  for (int r = 0; r < 4; r++){
#pragma unroll
    for (int off = 1; off < 16; off <<= 1)
      lp[r] += __shfl_xor(lp[r], off);
  }

#pragma unroll
  for (int r = 0; r < 4; r++){
    float inv = 1.0f / lp[r];
    int q = q0 + w * 16 + quad * 4 + r;
    size_t rb = ((size_t)(b * 2048 + q)) * 512 + h * 64;
#pragma unroll
    for (int ni = 0; ni < 4; ni++)
      Oh[rb + ni * 16 + l15] = f2bf(Oacc[ni][r] * inv);
  }
}

extern "C" void kernel_launch(void* const* d_in, const int* in_sizes, int n_in,
                              void* d_out, int out_size, void* d_ws, size_t ws_size,
                              hipStream_t stream)
{
  const float* gene = (const float*)d_in[0];
  const float* expr = (const float*)d_in[1];
  const float* Mm   = (const float*)d_in[2];
  const float* Wf   = (const float*)d_in[3];
  const float* bfv  = (const float*)d_in[4];
  const float* Wq   = (const float*)d_in[5];
  const float* bq   = (const float*)d_in[6];
  const float* Wk   = (const float*)d_in[7];
  const float* bk   = (const float*)d_in[8];
  const float* Wv   = (const float*)d_in[9];
  const float* bv   = (const float*)d_in[10];
  const float* Wo   = (const float*)d_in[11];
  const float* bo   = (const float*)d_in[12];
  float* out = (float*)d_out;

  char* ws = (char*)d_ws;
  size_t off = 0;
  auto alloc = [&](size_t bytes) -> void* {
    void* p = (void*)(ws + off);
    off += (bytes + 255) & ~(size_t)255;
    return p;
  };
  u16* Xh   = (u16*)alloc(8192ull * 1024 * 2);
  u16* Xl   = (u16*)alloc(8192ull * 1024 * 2);
  u16* Wfth = (u16*)alloc(512ull * 1024 * 2);
  u16* Wftl = (u16*)alloc(512ull * 1024 * 2);
  u16* Wqth = (u16*)alloc(512ull * 512 * 2);
  u16* Wkth = (u16*)alloc(512ull * 512 * 2);
  u16* Wvth = (u16*)alloc(512ull * 512 * 2);
  u16* Woth = (u16*)alloc(512ull * 512 * 2);
  u16* Fh   = (u16*)alloc(8192ull * 512 * 2);
  u16* Fl   = (u16*)alloc(8192ull * 512 * 2);
  u16* Qh   = (u16*)alloc(8192ull * 512 * 2);
  u16* Kh   = (u16*)alloc(8192ull * 512 * 2);
  u16* Vt   = (u16*)alloc(8192ull * 512 * 2);
  u16* Oh = Xh;   // X dead after QKV; attention output aliases it

  const float QSC = 0.1803368801f;   // 0.125 * log2(e) — folded into Q, exp via exp2

  prep_kernel<<<8576, 256, 0, stream>>>(gene, expr, Wf, Wq, Wk, Wv, Wo,
                                        Xh, Xl, Wfth, Wftl, Wqth, Wkth, Wvth, Woth);
  gemm_fused_kernel<<<dim3(64, 8), 256, 0, stream>>>(Xh, Xl, Wfth, Wftl, bfv, Fh, Fl);
  gemm_qkv_kernel<<<dim3(64, 24), 256, 0, stream>>>(Fh, Fl, Xh + 512, Xl + 512,
                                                    Wqth, Wkth, Wvth, bq, bk, bv,
                                                    Qh, Kh, Vt, QSC);
  flash_kernel<<<dim3(32, 32), 256, 0, stream>>>(Qh, Kh, Vt, Mm, Oh);
  gemm_o_kernel<<<dim3(64, 8), 256, 0, stream>>>(Oh, Woth, bo, out);

  (void)in_sizes; (void)n_in; (void)out_size; (void)ws_size;
}

// Round 6
// 331.422 us; speedup vs baseline: 1.4142x; 1.0244x over previous
//
#include <hip/hip_runtime.h>

typedef unsigned short u16;
typedef __attribute__((ext_vector_type(8))) short bf16x8_t;
typedef __attribute__((ext_vector_type(4))) float f32x4_t;

__device__ __forceinline__ u16 f2bf(float x){
  union { float f; unsigned u; } v; v.f = x;
  unsigned r = v.u + 0x7FFFu + ((v.u >> 16) & 1u);
  return (u16)(r >> 16);
}
__device__ __forceinline__ float bf2f(u16 h){
  union { unsigned u; float f; } v; v.u = ((unsigned)h) << 16;
  return v.f;
}
__device__ __forceinline__ u16 hi16(float x){
  union { float f; unsigned u; } v; v.f = x;
  return (u16)(v.u >> 16);          // truncation: bias cancels in renormalization
}

// async global->LDS DMA, 16B/lane; data lands at base + lane*16.
__device__ __forceinline__ void gl2lds16(const u16* g, u16* l){
  __builtin_amdgcn_global_load_lds((const __attribute__((address_space(1))) void*)g,
                                   (__attribute__((address_space(3))) void*)l, 16, 0, 0);
}

// ---- prep: X=[gene|expr] hi/lo split (blocks 0..8191) + all W transposes (8192..8575)
__global__ __launch_bounds__(256) void prep_kernel(
    const float* __restrict__ gene, const float* __restrict__ expr,
    const float* __restrict__ Wf, const float* __restrict__ Wq,
    const float* __restrict__ Wk, const float* __restrict__ Wv,
    const float* __restrict__ Wo,
    u16* __restrict__ Xh, u16* __restrict__ Xl,
    u16* __restrict__ Wfth, u16* __restrict__ Wftl,
    u16* __restrict__ Wqth, u16* __restrict__ Wkth,
    u16* __restrict__ Wvth, u16* __restrict__ Woth)
{
  __shared__ float t[64][65];
  int tid = threadIdx.x;
  if (blockIdx.x < 8192){
    size_t e = ((size_t)blockIdx.x * 256 + tid) * 4;
    int row = (int)(e >> 10);
    int col = (int)(e & 1023);
    const float* src = (col < 512) ? (gene + (size_t)row * 512 + col)
                                   : (expr + (size_t)row * 512 + (col - 512));
    float4 v = *(const float4*)src;
    float a[4] = {v.x, v.y, v.z, v.w};
    u16 hs[4], ls[4];
#pragma unroll
    for (int i = 0; i < 4; i++){
      hs[i] = f2bf(a[i]);
      ls[i] = f2bf(a[i] - bf2f(hs[i]));
    }
    *(uint2*)(Xh + e) = make_uint2(hs[0] | ((unsigned)hs[1] << 16), hs[2] | ((unsigned)hs[3] << 16));
    *(uint2*)(Xl + e) = make_uint2(ls[0] | ((unsigned)ls[1] << 16), ls[2] | ((unsigned)ls[3] << 16));
    return;
  }
  int id = blockIdx.x - 8192;
  const float* W; u16* Th; u16* Tl; int K, kx, ny;
  if (id < 128){ W = Wf; Th = Wfth; Tl = Wftl; K = 1024; kx = id >> 3; ny = id & 7; }
  else {
    int tt = id - 128; int wi = tt >> 6; tt &= 63; kx = tt >> 3; ny = tt & 7; K = 512;
    W  = (wi == 0) ? Wq  : (wi == 1) ? Wk  : (wi == 2) ? Wv  : Wo;
    Th = (wi == 0) ? Wqth: (wi == 1) ? Wkth: (wi == 2) ? Wvth: Woth;
    Tl = nullptr;
  }
  int k0 = kx * 64, n0 = ny * 64;
  int r = tid >> 4;
  int c4 = (tid & 15) * 4;
#pragma unroll
  for (int p = 0; p < 4; p++){
    int k = p * 16 + r;
    float4 v = *(const float4*)(W + (size_t)(k0 + k) * 512 + n0 + c4);
    t[c4 + 0][k] = v.x; t[c4 + 1][k] = v.y; t[c4 + 2][k] = v.z; t[c4 + 3][k] = v.w;
  }
  __syncthreads();
#pragma unroll
  for (int p = 0; p < 4; p++){
    int n = p * 16 + r;
    u16 hs[4], ls[4];
#pragma unroll
    for (int i = 0; i < 4; i++){
      float x = t[n][c4 + i];
      hs[i] = f2bf(x);
      ls[i] = f2bf(x - bf2f(hs[i]));
    }
    size_t o = (size_t)(n0 + n) * K + k0 + c4;
    *(uint2*)(Th + o) = make_uint2(hs[0] | ((unsigned)hs[1] << 16), hs[2] | ((unsigned)hs[3] << 16));
    if (Tl)
      *(uint2*)(Tl + o) = make_uint2(ls[0] | ((unsigned)ls[1] << 16), ls[2] | ((unsigned)ls[3] << 16));
  }
}

// ---- double-buffered GEMM core: BM=128 BN=64, template BK (32 or 64) ----
// ONE barrier per BK-iter: sync -> issue DMA for tile i+1 (alt buffer) ->
// compute tile i. SPLITS: 3 = aH*bH+aH*bL+aL*bH ; 2 = aH*bH+aL*bH ; 1 = aH*bH
template<int SPLITS, int BK>
__device__ __forceinline__ void gemm_core_db(
    const u16* __restrict__ Ah, const u16* __restrict__ Al, int lda,
    const u16* __restrict__ Bh, const u16* __restrict__ Bl, int K,
    int m0, int n0, f32x4_t (&acc)[4][2],
    u16* sAh, u16* sAl, u16* sBh, u16* sBl)
{
  constexpr int NH  = BK / 32;
  constexpr int ASZ = 128 * BK;     // u16 elems per A buffer
  constexpr int BSZ = 64 * BK;
  int tid = threadIdx.x;
  int lane = tid & 63, w = tid >> 6, quad = lane >> 4, l15 = lane & 15;
  int wm = w & 1, wn = w >> 1;
  int lrow = lane >> 2;
  int swzS = ((lane >> 2) & 3) ^ ((lane >> 4) & 3);
  int gkq  = ((lane & 3) ^ swzS) * 8;
  const u16* pA0 = Ah + (size_t)(m0 + w * 32 + lrow) * lda + gkq;
  const u16* pA1 = Ah + (size_t)(m0 + w * 32 + 16 + lrow) * lda + gkq;
  const u16* pL0 = (SPLITS >= 2) ? Al + (size_t)(m0 + w * 32 + lrow) * lda + gkq : nullptr;
  const u16* pL1 = (SPLITS >= 2) ? Al + (size_t)(m0 + w * 32 + 16 + lrow) * lda + gkq : nullptr;
  const u16* pB0 = Bh + (size_t)(n0 + w * 16 + lrow) * K + gkq;
  const u16* pBl = (SPLITS == 3) ? Bl + (size_t)(n0 + w * 16 + lrow) * K + gkq : nullptr;
  int pq = (quad ^ ((l15 & 3) ^ ((l15 >> 2) & 3))) * 8;
  const int NIT = K / BK;

  auto stage = [&](int it){
    int bi = it & 1, k0 = it * BK;
    u16* dA = sAh + bi * ASZ + w * 1024;
    u16* dB = sBh + bi * BSZ + w * 512;
#pragma unroll
    for (int hf = 0; hf < NH; hf++){
      gl2lds16(pA0 + k0 + hf * 32, dA + hf * 4096);
      gl2lds16(pA1 + k0 + hf * 32, dA + hf * 4096 + 512);
      if constexpr (SPLITS >= 2){
        u16* dAl = sAl + bi * ASZ + w * 1024;
        gl2lds16(pL0 + k0 + hf * 32, dAl + hf * 4096);
        gl2lds16(pL1 + k0 + hf * 32, dAl + hf * 4096 + 512);
      }
      gl2lds16(pB0 + k0 + hf * 32, dB + hf * 2048);
      if constexpr (SPLITS == 3){
        u16* dBl = sBl + bi * BSZ + w * 512;
        gl2lds16(pBl + k0 + hf * 32, dBl + hf * 2048);
      }
    }
  };

  stage(0);
  for (int it = 0; it < NIT; ++it){
    int bi = it & 1;
    __syncthreads();                 // drains tile-i DMA (issued one iter ago)
    if (it + 1 < NIT) stage(it + 1);
#pragma unroll
    for (int hf = 0; hf < NH; hf++){
      bf16x8_t aH[4], aL[4], bH[2], bL[2];
#pragma unroll
      for (int mi = 0; mi < 4; mi++){
        int ad = (wm * 64 + mi * 16 + l15) * 32 + pq + bi * ASZ + hf * 4096;
        aH[mi] = *(const bf16x8_t*)&sAh[ad];
        if constexpr (SPLITS >= 2) aL[mi] = *(const bf16x8_t*)&sAl[ad];
      }
#pragma unroll
      for (int ni = 0; ni < 2; ni++){
        int bd = (wn * 32 + ni * 16 + l15) * 32 + pq + bi * BSZ + hf * 2048;
        bH[ni] = *(const bf16x8_t*)&sBh[bd];
        if constexpr (SPLITS == 3) bL[ni] = *(const bf16x8_t*)&sBl[bd];
      }
#pragma unroll
      for (int mi = 0; mi < 4; mi++)
#pragma unroll
        for (int ni = 0; ni < 2; ni++){
          acc[mi][ni] = __builtin_amdgcn_mfma_f32_16x16x32_bf16(aH[mi], bH[ni], acc[mi][ni], 0, 0, 0);
          if constexpr (SPLITS == 3)
            acc[mi][ni] = __builtin_amdgcn_mfma_f32_16x16x32_bf16(aH[mi], bL[ni], acc[mi][ni], 0, 0, 0);
          if constexpr (SPLITS >= 2)
            acc[mi][ni] = __builtin_amdgcn_mfma_f32_16x16x32_bf16(aL[mi], bH[ni], acc[mi][ni], 0, 0, 0);
        }
    }
  }
}

// fused = X @ Wf + bf -> split bf16. grid (64, 8). 48 KB LDS, 2 blocks/CU exact.
__global__ __launch_bounds__(256, 2) void gemm_fused_kernel(
    const u16* __restrict__ Xh, const u16* __restrict__ Xl,
    const u16* __restrict__ Wfth, const u16* __restrict__ Wftl,
    const float* __restrict__ bias, u16* __restrict__ Fh, u16* __restrict__ Fl)
{
  __shared__ __align__(16) u16 sAh[2 * 4096], sAl[2 * 4096], sBh[2 * 2048], sBl[2 * 2048];
  int m0 = blockIdx.x * 128, n0 = blockIdx.y * 64;
  f32x4_t acc[4][2];
#pragma unroll
  for (int i = 0; i < 4; i++)
#pragma unroll
    for (int j = 0; j < 2; j++)
#pragma unroll
      for (int r = 0; r < 4; r++) acc[i][j][r] = 0.f;
  gemm_core_db<3, 32>(Xh, Xl, 1024, Wfth, Wftl, 1024, m0, n0, acc, sAh, sAl, sBh, sBl);

  int lane = threadIdx.x & 63, w = threadIdx.x >> 6, quad = lane >> 4, l15 = lane & 15;
  int wm = w & 1, wn = w >> 1;
#pragma unroll
  for (int mi = 0; mi < 4; mi++)
#pragma unroll
    for (int ni = 0; ni < 2; ni++){
      int gn = n0 + wn * 32 + ni * 16 + l15;
      float bs = bias[gn];
      int gm0 = m0 + wm * 64 + mi * 16 + quad * 4;
#pragma unroll
      for (int r = 0; r < 4; r++){
        float v = acc[mi][ni][r] + bs;
        u16 hb = f2bf(v);
        Fh[(size_t)(gm0 + r) * 512 + gn] = hb;
        Fl[(size_t)(gm0 + r) * 512 + gn] = f2bf(v - bf2f(hb));
      }
    }
}

// Q|K|V in one launch. grid (64, 24): side = y>>3 (0=Q,1=K,2=V), n0=(y&7)*64.
// 40 KB live LDS + 12 KB pad -> exactly 3 blocks/CU (grid 1536 = 3 exact waves).
__global__ __launch_bounds__(256, 3) void gemm_qkv_kernel(
    const u16* __restrict__ Fh, const u16* __restrict__ Fl,
    const u16* __restrict__ Xeh, const u16* __restrict__ Xel,   // expr half of X, lda 1024
    const u16* __restrict__ Wqth, const u16* __restrict__ Wkth, const u16* __restrict__ Wvth,
    const float* __restrict__ bq, const float* __restrict__ bk, const float* __restrict__ bv,
    u16* __restrict__ Q, u16* __restrict__ Kout, u16* __restrict__ Vt, int K, float qsc)
{
  __shared__ __align__(16) u16 sAh[2 * 4096], sAl[2 * 4096], sBh[2 * 2048];
  __shared__ u16 sPad[6144];   // occupancy shaper: 53248 B -> 3 blocks/CU
  if (K == 0){ sPad[threadIdx.x] = 0; __syncthreads(); sAh[0] = sPad[0]; }

  int side = blockIdx.y >> 3;
  int m0 = blockIdx.x * 128, n0 = (blockIdx.y & 7) * 64;
  const u16* Ah = (side == 2) ? Xeh : Fh;
  const u16* Al = (side == 2) ? Xel : Fl;
  int lda = (side == 2) ? 1024 : 512;
  const u16* Bh = (side == 0) ? Wqth : (side == 1) ? Wkth : Wvth;
  const float* bias = (side == 0) ? bq : (side == 1) ? bk : bv;

  f32x4_t acc[4][2];
#pragma unroll
  for (int i = 0; i < 4; i++)
#pragma unroll
    for (int j = 0; j < 2; j++)
#pragma unroll
      for (int r = 0; r < 4; r++) acc[i][j][r] = 0.f;
  gemm_core_db<2, 32>(Ah, Al, lda, Bh, nullptr, K, m0, n0, acc, sAh, sAl, sBh, nullptr);

  int lane = threadIdx.x & 63, w = threadIdx.x >> 6, quad = lane >> 4, l15 = lane & 15;
  int wm = w & 1, wn = w >> 1;
#pragma unroll
  for (int mi = 0; mi < 4; mi++)
#pragma unroll
    for (int ni = 0; ni < 2; ni++){
      int gn = n0 + wn * 32 + ni * 16 + l15;
      float bs = bias[gn];
      int gm0 = m0 + wm * 64 + mi * 16 + quad * 4;
#pragma unroll
      for (int r = 0; r < 4; r++){
        float v = acc[mi][ni][r] + bs;
        int gm = gm0 + r;
        if (side == 0){
          Q[(size_t)gm * 512 + gn] = f2bf(v * qsc);
        } else if (side == 1){
          Kout[(size_t)gm * 512 + gn] = f2bf(v);
        } else {
          int bb = gm >> 11, s = gm & 2047;
          int hh = gn >> 6, d = gn & 63;
          Vt[((size_t)((bb * 8 + hh) * 64 + d) << 11) + s] = f2bf(v);
        }
      }
    }
}

// out = O @ Wo + bo -> f32. grid (64, 8). 48 KB, 2 blocks/CU exact.
__global__ __launch_bounds__(256, 2) void gemm_o_kernel(
    const u16* __restrict__ Oh, const u16* __restrict__ Woth,
    const float* __restrict__ bias, float* __restrict__ out)
{
  __shared__ __align__(16) u16 sAh[2 * 8192], sBh[2 * 4096];
  int m0 = blockIdx.x * 128, n0 = blockIdx.y * 64;
  f32x4_t acc[4][2];
#pragma unroll
  for (int i = 0; i < 4; i++)
#pragma unroll
    for (int j = 0; j < 2; j++)
#pragma unroll
      for (int r = 0; r < 4; r++) acc[i][j][r] = 0.f;
  gemm_core_db<1, 64>(Oh, nullptr, 512, Woth, nullptr, 512, m0, n0, acc, sAh, nullptr, sBh, nullptr);

  int lane = threadIdx.x & 63, w = threadIdx.x >> 6, quad = lane >> 4, l15 = lane & 15;
  int wm = w & 1, wn = w >> 1;
#pragma unroll
  for (int mi = 0; mi < 4; mi++)
#pragma unroll
    for (int ni = 0; ni < 2; ni++){
      int gn = n0 + wn * 32 + ni * 16 + l15;
      float bs = bias[gn];
      int gm0 = m0 + wm * 64 + mi * 16 + quad * 4;
#pragma unroll
      for (int r = 0; r < 4; r++)
        out[(size_t)(gm0 + r) * 512 + gn] = acc[mi][ni][r] + bs;
    }
}

// ---- flash attention: 32 q/wave (2 q-frags), 2-wave blocks of 64 q,
// double-buffered K/V, ONE barrier per iter. K/V fragment reads amortize
// over 2 q-frags (halves LDS read traffic vs 16q/wave).
// LDS = 16(K dbuf) + 16(V dbuf) + 8(sP) = 40 KiB -> 4 blocks/CU, grid 1024 exact.
// Q pre-scaled by 0.125*log2(e); p = M*exp2(s*M); l = sum p; O = (sum p*V)/l.
__global__ __launch_bounds__(128, 2) void flash_kernel(
    const u16* __restrict__ Qh, const u16* __restrict__ Kh,
    const u16* __restrict__ Vt, const float* __restrict__ Mm,
    u16* __restrict__ Oh)
{
  __shared__ __align__(16) u16 sKh[2 * 4096], sVt[2 * 4096], sP[2 * 2048];
  int tid = threadIdx.x, lane = tid & 63, w = tid >> 6, quad = lane >> 4, l15 = lane & 15;
  int bh = blockIdx.y, b = bh >> 3, h = bh & 7;
  int q0 = blockIdx.x * 64;
  int qbase = q0 + w * 32;

  // Q fragments (2 q-frags x 2 k-halves)
  bf16x8_t qH[2][2];
#pragma unroll
  for (int qf = 0; qf < 2; qf++){
    const u16* qp = Qh + ((size_t)(b * 2048 + qbase + qf * 16 + l15)) * 512 + h * 64 + quad * 8;
    qH[qf][0] = *(const bf16x8_t*)qp;
    qH[qf][1] = *(const bf16x8_t*)(qp + 32);
  }

  float lp[2][4];
  f32x4_t Oacc[2][4];
#pragma unroll
  for (int qf = 0; qf < 2; qf++)
#pragma unroll
    for (int ni = 0; ni < 4; ni++){
      lp[qf][ni] = 0.f;
#pragma unroll
      for (int r = 0; r < 4; r++) Oacc[qf][ni][r] = 0.f;
    }

  // staging: wave w stages rows [w*32, w*32+32) of the 64-row K and V tiles.
  // row granule g holds cols (g ^ (row&7))*8.. -> fragment reads 2-way banked.
  int srow = lane >> 3;
  int gc = ((lane & 7) ^ srow) * 8;
  const u16* gK = Kh + ((size_t)(b * 2048 + w * 32 + srow)) * 512 + h * 64 + gc;
  const u16* gV = Vt + ((size_t)(bh * 64 + w * 32 + srow)) * 2048 + gc;

  auto stage = [&](int it){
    int bi = it & 1, k0 = it * 64;
    u16* dK = sKh + bi * 4096 + w * 2048;
    u16* dV = sVt + bi * 4096 + w * 2048;
#pragma unroll
    for (int i = 0; i < 4; i++){
      gl2lds16(gK + (size_t)(k0 + i * 8) * 512, dK + i * 512);
      gl2lds16(gV + (size_t)k0 + (size_t)(i * 8) * 2048, dV + i * 512);
    }
  };

  const float* pMb = Mm + (size_t)b * 2048 * 2048 + l15;
  // M for tile 0
  float Mc[2][4][4];
#pragma unroll
  for (int qf = 0; qf < 2; qf++)
#pragma unroll
    for (int ni = 0; ni < 4; ni++)
#pragma unroll
      for (int r = 0; r < 4; r++)
        Mc[qf][ni][r] = pMb[(size_t)(qbase + qf * 16 + quad * 4 + r) * 2048 + ni * 16];

  stage(0);
  int sw7 = l15 & 7;
  for (int it = 0; it < 32; ++it){
    int bi = it & 1;
    const u16* cK = sKh + bi * 4096;
    const u16* cV = sVt + bi * 4096;
    __syncthreads();                 // drains tile-i DMA (issued one iter ago)
    bool hasNext = (it + 1) < 32;
    if (hasNext) stage(it + 1);

    // prefetch next tile's M (consumed next iteration)
    float Mn[2][4][4];
    if (hasNext){
      int kn = (it + 1) * 64;
#pragma unroll
      for (int qf = 0; qf < 2; qf++)
#pragma unroll
        for (int ni = 0; ni < 4; ni++)
#pragma unroll
          for (int r = 0; r < 4; r++)
            Mn[qf][ni][r] = pMb[(size_t)(qbase + qf * 16 + quad * 4 + r) * 2048 + kn + ni * 16];
    }

    // K fragments (shared across both q-frags)
    bf16x8_t kf[4][2];
#pragma unroll
    for (int ni = 0; ni < 4; ni++)
#pragma unroll
      for (int ds = 0; ds < 2; ds++)
        kf[ni][ds] = *(const bf16x8_t*)&cK[(ni * 16 + l15) * 64 + (((ds * 4 + quad) ^ sw7)) * 8];

    // scores
    f32x4_t S[2][4];
#pragma unroll
    for (int qf = 0; qf < 2; qf++)
#pragma unroll
      for (int ni = 0; ni < 4; ni++){
#pragma unroll
        for (int r = 0; r < 4; r++) S[qf][ni][r] = 0.f;
        S[qf][ni] = __builtin_amdgcn_mfma_f32_16x16x32_bf16(qH[qf][0], kf[ni][0], S[qf][ni], 0, 0, 0);
        S[qf][ni] = __builtin_amdgcn_mfma_f32_16x16x32_bf16(qH[qf][1], kf[ni][1], S[qf][ni], 0, 0, 0);
      }

    // p = M*exp2(s*M); per-lane l; truncation-store bf16 P (wave-private, swizzled)
#pragma unroll
    for (int qf = 0; qf < 2; qf++)
#pragma unroll
      for (int ni = 0; ni < 4; ni++)
#pragma unroll
        for (int r = 0; r < 4; r++){
          float m = Mc[qf][ni][r];
          float p = m * __builtin_amdgcn_exp2f(S[qf][ni][r] * m);
          lp[qf][r] += p;
          int row = qf * 16 + quad * 4 + r;
          int sws = (row ^ (row >> 3)) & 7;
          sP[w * 2048 + row * 64 + (((ni * 2 + (l15 >> 3)) ^ sws) * 8) + (l15 & 7)] = hi16(p);
        }

    // V fragments + PV
    bf16x8_t vf[4][2];
#pragma unroll
    for (int ni = 0; ni < 4; ni++)
#pragma unroll
      for (int ds = 0; ds < 2; ds++)
        vf[ni][ds] = *(const bf16x8_t*)&cV[(ni * 16 + l15) * 64 + (((ds * 4 + quad) ^ sw7)) * 8];
#pragma unroll
    for (int qf = 0; qf < 2; qf++){
      int rowr = qf * 16 + l15;
      int swr = (rowr ^ (rowr >> 3)) & 7;
#pragma unroll
      for (int ds = 0; ds < 2; ds++){
        bf16x8_t pf = *(const bf16x8_t*)&sP[w * 2048 + rowr * 64 + (((ds * 4 + quad) ^ swr) * 8)];
#pragma unroll
        for (int ni = 0; ni < 4; ni++)
          Oacc[qf][ni] = __builtin_amdgcn_mfma_f32_16x16x32_bf16(pf, vf[ni][ds], Oacc[qf][ni], 0, 0, 0);
      }
    }

    if (hasNext){
#pragma unroll
      for (int qf = 0; qf < 2; qf++)
#pragma unroll
        for (int ni = 0; ni < 4; ni++)
#pragma unroll
          for (int r = 0; r < 4; r++) Mc[qf][ni][r] = Mn[qf][ni][r];
    }
  }

#pragma unroll
  for (int qf = 0; qf < 2; qf++)
#pragma unroll
    for (int r = 0; r < 4; r++){
#pragma unroll
      for (int off = 1; off < 16; off <<= 1)
        lp[qf][r] += __shfl_xor(lp[qf][r], off);
    }

#pragma unroll
  for (int qf = 0; qf < 2; qf++)
#pragma unroll
    for (int r = 0; r < 4; r++){
      float inv = 1.0f / lp[qf][r];
      int q = qbase + qf * 16 + quad * 4 + r;
      size_t rb = ((size_t)(b * 2048 + q)) * 512 + h * 64;
#pragma unroll
      for (int ni = 0; ni < 4; ni++)
        Oh[rb + ni * 16 + l15] = f2bf(Oacc[qf][ni][r] * inv);
    }
}

extern "C" void kernel_launch(void* const* d_in, const int* in_sizes, int n_in,
                              void* d_out, int out_size, void* d_ws, size_t ws_size,
                              hipStream_t stream)
{
  const float* gene = (const float*)d_in[0];
  const float* expr = (const float*)d_in[1];
  const float* Mm   = (const float*)d_in[2];
  const float* Wf   = (const float*)d_in[3];
  const float* bfv  = (const float*)d_in[4];
  const float* Wq   = (const float*)d_in[5];
  const float* bq   = (const float*)d_in[6];
  const float* Wk   = (const float*)d_in[7];
  const float* bk   = (const float*)d_in[8];
  const float* Wv   = (const float*)d_in[9];
  const float* bv   = (const float*)d_in[10];
  const float* Wo   = (const float*)d_in[11];
  const float* bo   = (const float*)d_in[12];
  float* out = (float*)d_out;

  char* ws = (char*)d_ws;
  size_t off = 0;
  auto alloc = [&](size_t bytes) -> void* {
    void* p = (void*)(ws + off);
    off += (bytes + 255) & ~(size_t)255;
    return p;
  };
  u16* Xh   = (u16*)alloc(8192ull * 1024 * 2);
  u16* Xl   = (u16*)alloc(8192ull * 1024 * 2);
  u16* Wfth = (u16*)alloc(512ull * 1024 * 2);
  u16* Wftl = (u16*)alloc(512ull * 1024 * 2);
  u16* Wqth = (u16*)alloc(512ull * 512 * 2);
  u16* Wkth = (u16*)alloc(512ull * 512 * 2);
  u16* Wvth = (u16*)alloc(512ull * 512 * 2);
  u16* Woth = (u16*)alloc(512ull * 512 * 2);
  u16* Fh   = (u16*)alloc(8192ull * 512 * 2);
  u16* Fl   = (u16*)alloc(8192ull * 512 * 2);
  u16* Qh   = (u16*)alloc(8192ull * 512 * 2);
  u16* Kh   = (u16*)alloc(8192ull * 512 * 2);
  u16* Vt   = (u16*)alloc(8192ull * 512 * 2);
  u16* Oh = Xh;   // X dead after QKV; attention output aliases it

  const float QSC = 0.1803368801f;   // 0.125 * log2(e) — folded into Q, exp via exp2

  prep_kernel<<<8576, 256, 0, stream>>>(gene, expr, Wf, Wq, Wk, Wv, Wo,
                                        Xh, Xl, Wfth, Wftl, Wqth, Wkth, Wvth, Woth);
  gemm_fused_kernel<<<dim3(64, 8), 256, 0, stream>>>(Xh, Xl, Wfth, Wftl, bfv, Fh, Fl);
  gemm_qkv_kernel<<<dim3(64, 24), 256, 0, stream>>>(Fh, Fl, Xh + 512, Xl + 512,
                                                    Wqth, Wkth, Wvth, bq, bk, bv,
                                                    Qh, Kh, Vt, 512, QSC);
  flash_kernel<<<dim3(32, 32), 128, 0, stream>>>(Qh, Kh, Vt, Mm, Oh);
  gemm_o_kernel<<<dim3(64, 8), 256, 0, stream>>>(Oh, Woth, bo, out);

  (void)in_sizes; (void)n_in; (void)out_size; (void)ws_size;
}